// Round 1
// baseline (710.097 us; speedup 1.0000x reference)
//
#include <hip/hip_runtime.h>
#include <hip/hip_fp16.h>

// CapsuleLayer dynamic routing — round 5: single persistent kernel.
// One block = one batch element b (grid 256 = 1 block/CU, LDS-limited by design).
// W (fp16, 2.95MB) streams once per block from XCD-L2; hat[i,j,d] for the whole
// batch element lives in registers (45 pairs/wave x 4 h2 = 180 VGPRs, fp16).
// All 3 routing rounds run in LDS: exp/Z tables, LDS-atomic s-reduction, squash,
// cumulative v — no device atomics, no inter-round global traffic, 2 launches.

#define IC 1152
#define IE 8
#define NC 10
#define DV 16
#define NB 256
#define NW (IC * NC * IE * DV)  // 1,474,560
#define SOUT (NC * DV)          // 160
#define TPB 512                 // 8 waves
#define NPAIR ((IC / 32) * NC)  // 360 (Gp,j) pairs
#define PPW (NPAIR / (TPB / 64))  // 45 pairs per wave

typedef _Float16 h2 __attribute__((ext_vector_type(2)));
union WChunk { int4 v; h2 p[4]; _Float16 h[8]; };
union XFrag { int4 v; h2 p[4]; };

#if defined(__has_builtin) && __has_builtin(__builtin_amdgcn_fdot2)
__device__ inline float fdot2(h2 a, h2 b, float c) {
    return __builtin_amdgcn_fdot2(a, b, c, false);
}
#else
__device__ inline float fdot2(h2 a, h2 b, float c) {
    return fmaf((float)a.x, (float)b.x, fmaf((float)a.y, (float)b.y, c));
}
#endif

// W fp32 [i][j][e][d] -> fp16 chunks Wc[((Gp*10+j)*8+k)*64 + lane], where
// lane = h*32+r, i = Gp*32+r, d = h*8+k; chunk holds e=0..7 halves of W[i,j,:,d].
__global__ void wprep_kernel(const float* __restrict__ W, int4* __restrict__ Wc) {
    const int t = blockIdx.x * blockDim.x + threadIdx.x;
    if (t >= NW / 8) return;
    const int lane = t & 63;
    const int h = lane >> 5, r = lane & 31;
    const int k = (t >> 6) & 7;
    const int r2 = t >> 9;  // Gp*10 + j
    const int j = r2 % NC, Gp = r2 / NC;
    const int i = Gp * 32 + r;
    const int d = h * 8 + k;
    const float* src = W + ((size_t)(i * NC + j) * IE) * DV + d;  // e-stride DV
    WChunk c;
#pragma unroll
    for (int e = 0; e < IE; ++e) c.h[e] = (_Float16)src[(size_t)e * DV];
    Wc[t] = c.v;
}

__global__ __launch_bounds__(TPB, 2) void caps_kernel(
    const float* __restrict__ X,     // [B, IC, IE] fp32
    const int4* __restrict__ Wc,     // coalesced fp16 layout (see wprep)
    const float* __restrict__ bias,  // [IC*NC] fp32
    float* __restrict__ out)         // [B, NC, DV]
{
    // LDS budget: 46080 + 46080 + 4608 + 640 + 640 + 320 = ~96 KB -> 1 block/CU
    __shared__ __align__(16) float bias_s[NC * IC];  // [j][i]
    __shared__ __align__(16) float U[NC * IC];       // union: packed-h2 X (hat phase) / exp(lt) table (rounds)
    __shared__ float Zs[IC];                         // per-row softmax denom, then 1/Z
    __shared__ float s_s[SOUT];                      // s[j*16+d] accumulator
    __shared__ float vc[SOUT];                       // cumulative v (f32)
    __shared__ __align__(16) h2 v2[SOUT / 2];        // cumulative v packed for fdot2

    const int b = blockIdx.x;
    const int tid = threadIdx.x;
    const int w = tid >> 6;   // wave 0..7
    const int g = tid & 63;
    const int h = g >> 5;     // d-half
    const int r = g & 31;     // row within 32-row group

    // ---- stage bias -> bias_s[j][i] (global read coalesced) ----
    for (int idx = tid; idx < IC * NC; idx += TPB) {
        const int i = idx / NC, j = idx - i * NC;
        bias_s[j * IC + i] = bias[idx];
    }
    // ---- stage X[b] packed as h2 into U: 16B per row i ----
    {
        const float4* xb = (const float4*)(X + (size_t)b * IC * IE);
        h2* xp = (h2*)U;
        for (int f = tid; f < IC * IE / 4; f += TPB) {  // 2304 float4
            const float4 v = xb[f];
            xp[f * 2 + 0] = h2{(_Float16)v.x, (_Float16)v.y};
            xp[f * 2 + 1] = h2{(_Float16)v.z, (_Float16)v.w};
        }
    }
    __syncthreads();

    // ---- hat phase: stream W once, keep hat resident in regs (fp16) ----
    // pair p = w*45+pp -> (Gp = p/10, j = p%10); lane covers i=Gp*32+r, d=h*8+0..7
    h2 hat2[PPW][4];
    {
        const h2* xp = (const h2*)U;
#pragma unroll
        for (int pp = 0; pp < PPW; ++pp) {
            const int p = w * PPW + pp;
            const int Gp = p / 10;
            const int i = Gp * 32 + r;
            XFrag xu;
            xu.v = *(const int4*)(xp + (size_t)i * 4);
            const int4* wp = Wc + (size_t)p * 512 + g;
            WChunk wk[8];
#pragma unroll
            for (int k = 0; k < 8; ++k) wk[k].v = wp[k * 64];
            float hat[8];
#pragma unroll
            for (int k = 0; k < 8; ++k) {
                float a = 0.f;
#pragma unroll
                for (int q = 0; q < 4; ++q) a = fdot2(xu.p[q], wk[k].p[q], a);
                hat[k] = a;
            }
#pragma unroll
            for (int q = 0; q < 4; ++q)
                hat2[pp][q] = h2{(_Float16)hat[2 * q], (_Float16)hat[2 * q + 1]};
        }
    }

    // ---- 3 routing rounds, fully in-LDS ----
    for (int rd = 0; rd < 3; ++rd) {
        for (int idx = tid; idx < IC; idx += TPB) Zs[idx] = 0.f;
        if (tid < SOUT) s_s[tid] = 0.f;
        __syncthreads();  // also orders U(x-reads) before U(explt-writes) on rd==0

        // loop1: logits -> exp table + Z
#pragma unroll
        for (int pp = 0; pp < PPW; ++pp) {
            const int p = w * PPW + pp;
            const int Gp = p / 10, j = p - Gp * 10;
            const int i = Gp * 32 + r;
            float lt = bias_s[j * IC + i];
            if (rd > 0) {
                XFrag vv;
                vv.v = *(const int4*)(v2 + (j * 8 + h * 4));
                float ah = 0.f;
#pragma unroll
                for (int q = 0; q < 4; ++q) ah = fdot2(hat2[pp][q], vv.p[q], ah);
                lt += ah + __shfl_xor(ah, 32);
            }
            if (h == 0) {
                const float e = __expf(lt);
                atomicAdd(&Zs[i], e);
                U[j * IC + i] = e;
            }
        }
        __syncthreads();
        for (int idx = tid; idx < IC; idx += TPB) Zs[idx] = 1.f / Zs[idx];
        __syncthreads();

        // loop2: c*hat, butterfly-reduce over the 32 r-lanes, LDS-atomic into s
#pragma unroll
        for (int pp = 0; pp < PPW; ++pp) {
            const int p = w * PPW + pp;
            const int Gp = p / 10, j = p - Gp * 10;
            const int i = Gp * 32 + r;
            const float c = U[j * IC + i] * Zs[i];
            float s8[8];
#pragma unroll
            for (int q = 0; q < 4; ++q) {
                s8[2 * q]     = c * (float)hat2[pp][q].x;
                s8[2 * q + 1] = c * (float)hat2[pp][q].y;
            }
            float t4[4];
#pragma unroll
            for (int d = 0; d < 4; ++d) {
                const bool hi = (r & 16);
                const float mine = hi ? s8[d + 4] : s8[d];
                const float send = hi ? s8[d] : s8[d + 4];
                t4[d] = mine + __shfl_xor(send, 16);
            }
            float t2[2];
#pragma unroll
            for (int d = 0; d < 2; ++d) {
                const bool hi = (r & 8);
                const float mine = hi ? t4[d + 2] : t4[d];
                const float send = hi ? t4[d] : t4[d + 2];
                t2[d] = mine + __shfl_xor(send, 8);
            }
            float t1;
            {
                const bool hi = (r & 4);
                const float mine = hi ? t2[1] : t2[0];
                const float send = hi ? t2[0] : t2[1];
                t1 = mine + __shfl_xor(send, 4);
            }
            t1 += __shfl_xor(t1, 2);
            t1 += __shfl_xor(t1, 1);
            if ((r & 3) == 0) {
                const int dl = (r >> 2) & 7;  // bit map: r4->d2, r3->d1, r2->d0
                atomicAdd(&s_s[j * DV + h * 8 + dl], t1);
            }
        }
        __syncthreads();

        // squash + cumulative-v update (or final output)
        if (tid < SOUT) {
            const float sv = s_s[tid];
            float s2 = sv * sv;
#pragma unroll
            for (int mk = 8; mk >= 1; mk >>= 1) s2 += __shfl_xor(s2, mk, 16);
            const float scale = sqrtf(s2) / (1.f + s2);
            const float vv = scale * sv;
            if (rd == 2) {
                out[(size_t)b * SOUT + tid] = vv;
            } else {
                const float vcum = (rd == 0) ? vv : (vc[tid] + vv);
                vc[tid] = vcum;
                const float oth = __shfl_xor(vcum, 1);
                if (!(tid & 1)) v2[tid >> 1] = h2{(_Float16)vcum, (_Float16)oth};
            }
        }
        __syncthreads();
    }
}

extern "C" void kernel_launch(void* const* d_in, const int* in_sizes, int n_in,
                              void* d_out, int out_size, void* d_ws, size_t ws_size,
                              hipStream_t stream) {
    const float* X = (const float*)d_in[0];     // [256,1152,8]
    const float* W = (const float*)d_in[1];     // [1152,10,8,16]
    const float* bias = (const float*)d_in[2];  // [1,1152,10]
    float* out = (float*)d_out;

    int4* Wc = (int4*)d_ws;  // ws: Wc only (2.95 MB)

    wprep_kernel<<<dim3(720), dim3(256), 0, stream>>>(W, Wc);
    caps_kernel<<<dim3(NB), dim3(TPB), 0, stream>>>(X, Wc, bias, out);
}

// Round 2
// 590.300 us; speedup vs baseline: 1.2029x; 1.2029x over previous
//
#include <hip/hip_runtime.h>
#include <hip/hip_fp16.h>

// CapsuleLayer dynamic routing — round 6: persistent kernel, spill-free register plan.
// One block = one batch element (grid 256 = 1 block/CU). 9 waves x 64; wave w owns
// Gp in {4w..4w+3} x all j (40 pairs/thread, hat2 = 160 VGPRs fp16; cap at 9 waves
// = 227 VGPRs -> fits). W fp16 (2.95MB) streams once per block from XCD-L2.
// Rounds fully in LDS: exp table + Z sum-pass (no atomics), per-wave exclusive
// s_part slabs (no atomics), squash + cumulative v in-block. 2 launches total.

#define IC 1152
#define IE 8
#define NC 10
#define DV 16
#define NB 256
#define NW (IC * NC * IE * DV)  // 1,474,560
#define SOUT (NC * DV)          // 160
#define NWAVE 9
#define TPB (NWAVE * 64)        // 576
#define NGPW 4                  // Gp groups per wave (36 = 9*4)
#define PPW (NGPW * NC)         // 40 pairs per thread

typedef _Float16 h2 __attribute__((ext_vector_type(2)));
union WChunk { int4 v; h2 p[4]; _Float16 h[8]; };
union XFrag { int4 v; h2 p[4]; };

#if defined(__has_builtin) && __has_builtin(__builtin_amdgcn_fdot2)
__device__ inline float fdot2(h2 a, h2 b, float c) {
    return __builtin_amdgcn_fdot2(a, b, c, false);
}
#else
__device__ inline float fdot2(h2 a, h2 b, float c) {
    return fmaf((float)a.x, (float)b.x, fmaf((float)a.y, (float)b.y, c));
}
#endif

// W fp32 [i][j][e][d] -> fp16 chunks Wc[((Gp*10+j)*8+k)*64 + lane], where
// lane = h*32+r, i = Gp*32+r, d = h*8+k; chunk holds e=0..7 halves of W[i,j,:,d].
__global__ void wprep_kernel(const float* __restrict__ W, int4* __restrict__ Wc) {
    const int t = blockIdx.x * blockDim.x + threadIdx.x;
    if (t >= NW / 8) return;
    const int lane = t & 63;
    const int h = lane >> 5, r = lane & 31;
    const int k = (t >> 6) & 7;
    const int r2 = t >> 9;  // Gp*10 + j
    const int j = r2 % NC, Gp = r2 / NC;
    const int i = Gp * 32 + r;
    const int d = h * 8 + k;
    const float* src = W + ((size_t)(i * NC + j) * IE) * DV + d;  // e-stride DV
    WChunk c;
#pragma unroll
    for (int e = 0; e < IE; ++e) c.h[e] = (_Float16)src[(size_t)e * DV];
    Wc[t] = c.v;
}

__global__ __launch_bounds__(TPB) void caps_kernel(
    const float* __restrict__ X,     // [B, IC, IE] fp32
    const int4* __restrict__ Wc,     // coalesced fp16 layout (see wprep)
    const float* __restrict__ bias,  // [IC*NC] fp32
    float* __restrict__ out)         // [B, NC, DV]
{
    // LDS: 46080 + 46080 + 4608 + 5760 + 640 + 320 = 103,488 B -> 1 block/CU
    __shared__ __align__(16) float bias_s[NC * IC];  // [j][i]
    __shared__ __align__(16) float U[NC * IC];       // union: packed-h2 X (hat phase) / exp(lt) table (rounds)
    __shared__ float Zs[IC];                         // 1/sum_j exp(lt)
    __shared__ float s_part[NWAVE * SOUT];           // per-wave exclusive s slabs
    __shared__ float vc[SOUT];                       // cumulative v (f32)
    __shared__ __align__(16) h2 v2[SOUT / 2];        // cumulative v packed for fdot2

    const int b = blockIdx.x;
    const int tid = threadIdx.x;
    const int w = tid >> 6;   // wave 0..8
    const int g = tid & 63;
    const int h = g >> 5;     // d-half: d = h*8 + k
    const int r = g & 31;     // row within 32-row group

    // ---- stage bias -> bias_s[j][i] ----
    for (int idx = tid; idx < IC * NC; idx += TPB) {
        const int i = idx / NC, j = idx - i * NC;
        bias_s[j * IC + i] = bias[idx];
    }
    // ---- stage X[b] packed as h2 into U: 16B per row i ----
    {
        const float4* xb = (const float4*)(X + (size_t)b * IC * IE);
        h2* xp = (h2*)U;
        for (int f = tid; f < IC * IE / 4; f += TPB) {  // 2304 float4, 4 iters
            const float4 v = xb[f];
            xp[f * 2 + 0] = h2{(_Float16)v.x, (_Float16)v.y};
            xp[f * 2 + 1] = h2{(_Float16)v.z, (_Float16)v.w};
        }
    }
    __syncthreads();

    // ---- hat phase: stream W once, keep hat resident in regs (fp16, 160 VGPRs) ----
    h2 hat2[PPW][4];
    {
        const h2* xp = (const h2*)U;
#pragma unroll
        for (int gl = 0; gl < NGPW; ++gl) {
            const int Gp = NGPW * w + gl;
            const int i = Gp * 32 + r;
            XFrag xu;
            xu.v = *(const int4*)(xp + (size_t)i * 4);
#pragma unroll
            for (int j = 0; j < NC; ++j) {
                const int pp = gl * NC + j;
                const int4* wp = Wc + ((size_t)(Gp * NC + j)) * 512 + g;
                float hat[8];
                WChunk wk[4];
#pragma unroll
                for (int k = 0; k < 4; ++k) wk[k].v = wp[k * 64];
#pragma unroll
                for (int k = 0; k < 4; ++k) {
                    float a = 0.f;
#pragma unroll
                    for (int q = 0; q < 4; ++q) a = fdot2(xu.p[q], wk[k].p[q], a);
                    hat[k] = a;
                }
#pragma unroll
                for (int k = 0; k < 4; ++k) wk[k].v = wp[(k + 4) * 64];
#pragma unroll
                for (int k = 0; k < 4; ++k) {
                    float a = 0.f;
#pragma unroll
                    for (int q = 0; q < 4; ++q) a = fdot2(xu.p[q], wk[k].p[q], a);
                    hat[k + 4] = a;
                }
#pragma unroll
                for (int q = 0; q < 4; ++q)
                    hat2[pp][q] = h2{(_Float16)hat[2 * q], (_Float16)hat[2 * q + 1]};
            }
        }
    }

    // ---- 3 routing rounds, fully in-LDS ----
    for (int rd = 0; rd < 3; ++rd) {
        __syncthreads();  // U readers done (X in hat phase / prev loop2), v2 ready

        // loop1: logits -> exp table U[j][i]
        if (rd == 0) {
            for (int idx = tid; idx < IC * NC; idx += TPB)  // 20 iters
                U[idx] = __expf(bias_s[idx]);
        } else {
#pragma unroll
            for (int gl = 0; gl < NGPW; ++gl) {
                const int Gp = NGPW * w + gl;
                const int i = Gp * 32 + r;
#pragma unroll
                for (int j = 0; j < NC; ++j) {
                    const int pp = gl * NC + j;
                    XFrag vv;
                    vv.v = *(const int4*)(v2 + (j * 8 + h * 4));
                    float ah = 0.f;
#pragma unroll
                    for (int q = 0; q < 4; ++q) ah = fdot2(hat2[pp][q], vv.p[q], ah);
                    const float lt = bias_s[j * IC + i] + ah + __shfl_xor(ah, 32);
                    if (h == 0) U[j * IC + i] = __expf(lt);
                }
            }
        }
        __syncthreads();

        // Z pass: 1/sum_j exp  (2 iters per thread)
        for (int idx = tid; idx < IC; idx += TPB) {
            float Z = 0.f;
#pragma unroll
            for (int j = 0; j < NC; ++j) Z += U[j * IC + idx];
            Zs[idx] = 1.f / Z;
        }
        __syncthreads();

        // loop2: per-j accumulate c*hat over this wave's 4 Gp groups, one
        // butterfly per j, plain store into this wave's exclusive s_part slab
#pragma unroll
        for (int j = 0; j < NC; ++j) {
            float s8[8] = {0.f, 0.f, 0.f, 0.f, 0.f, 0.f, 0.f, 0.f};
#pragma unroll
            for (int gl = 0; gl < NGPW; ++gl) {
                const int Gp = NGPW * w + gl;
                const int i = Gp * 32 + r;
                const int pp = gl * NC + j;
                const float c = U[j * IC + i] * Zs[i];
#pragma unroll
                for (int q = 0; q < 4; ++q) {
                    s8[2 * q]     = fmaf(c, (float)hat2[pp][q].x, s8[2 * q]);
                    s8[2 * q + 1] = fmaf(c, (float)hat2[pp][q].y, s8[2 * q + 1]);
                }
            }
            // splitting butterfly over the 32 r-lanes of this d-half: 8->4->2->1
            float t4[4];
#pragma unroll
            for (int d = 0; d < 4; ++d) {
                const bool hi = (r & 16);
                const float mine = hi ? s8[d + 4] : s8[d];
                const float send = hi ? s8[d] : s8[d + 4];
                t4[d] = mine + __shfl_xor(send, 16);
            }
            float t2[2];
#pragma unroll
            for (int d = 0; d < 2; ++d) {
                const bool hi = (r & 8);
                const float mine = hi ? t4[d + 2] : t4[d];
                const float send = hi ? t4[d] : t4[d + 2];
                t2[d] = mine + __shfl_xor(send, 8);
            }
            float t1;
            {
                const bool hi = (r & 4);
                const float mine = hi ? t2[1] : t2[0];
                const float send = hi ? t2[0] : t2[1];
                t1 = mine + __shfl_xor(send, 4);
            }
            t1 += __shfl_xor(t1, 2);
            t1 += __shfl_xor(t1, 1);
            if ((r & 3) == 0) {
                const int dl = (r >> 2) & 7;  // bit map: r4->d2, r3->d1, r2->d0
                s_part[w * SOUT + j * DV + h * 8 + dl] = t1;
            }
        }
        __syncthreads();

        // squash: sum the 9 wave slabs, squash, update cumulative v / output
        if (tid < SOUT) {
            float sv = 0.f;
#pragma unroll
            for (int ww = 0; ww < NWAVE; ++ww) sv += s_part[ww * SOUT + tid];
            float s2 = sv * sv;
#pragma unroll
            for (int mk = 8; mk >= 1; mk >>= 1) s2 += __shfl_xor(s2, mk, 16);
            const float scale = sqrtf(s2) / (1.f + s2);
            const float vv = scale * sv;
            if (rd == 2) {
                out[(size_t)b * SOUT + tid] = vv;
            } else {
                const float vcum = (rd == 0) ? vv : (vc[tid] + vv);
                vc[tid] = vcum;
                const float oth = __shfl_xor(vcum, 1);
                if (!(tid & 1)) v2[tid >> 1] = h2{(_Float16)vcum, (_Float16)oth};
            }
        }
    }
}

extern "C" void kernel_launch(void* const* d_in, const int* in_sizes, int n_in,
                              void* d_out, int out_size, void* d_ws, size_t ws_size,
                              hipStream_t stream) {
    const float* X = (const float*)d_in[0];     // [256,1152,8]
    const float* W = (const float*)d_in[1];     // [1152,10,8,16]
    const float* bias = (const float*)d_in[2];  // [1,1152,10]
    float* out = (float*)d_out;

    int4* Wc = (int4*)d_ws;  // ws: Wc only (2.95 MB)

    wprep_kernel<<<dim3(720), dim3(256), 0, stream>>>(W, Wc);
    caps_kernel<<<dim3(NB), dim3(TPB), 0, stream>>>(X, Wc, bias, out);
}

// Round 3
// 416.300 us; speedup vs baseline: 1.7057x; 1.4180x over previous
//
#include <hip/hip_runtime.h>
#include <hip/hip_fp16.h>

// CapsuleLayer dynamic routing — round 7: fix the spill for real.
// Round-6 post-mortem: backend's default occupancy heuristic capped VGPRs at 84
// (~6 waves/EU) and sent hat2 to scratch (FETCH 366MB/WRITE 326MB of spill).
// Also: 9-wave workgroups have a HARD cap of 170 VGPRs (3 waves/SIMD, 512-reg
// file) which my 195-reg plan could never meet.
// New plan: 12 waves (768 thr), 3 Gp-groups/wave -> hat2 = [3][10][4] h2 = 120
// VGPRs; demand ~150 <= 170 hard cap; __launch_bounds__(768,1) pins the
// occupancy target so the RA actually uses the budget. Bias staging transposed
// to kill LDS write bank conflicts.

#define IC 1152
#define IE 8
#define NC 10
#define DV 16
#define NB 256
#define NW (IC * NC * IE * DV)  // 1,474,560
#define SOUT (NC * DV)          // 160
#define NWAVE 12
#define TPB (NWAVE * 64)        // 768
#define NGPW 3                  // Gp groups per wave (36 = 12*3)

typedef _Float16 h2 __attribute__((ext_vector_type(2)));
union WChunk { int4 v; h2 p[4]; _Float16 h[8]; };
union XFrag { int4 v; h2 p[4]; };

#if defined(__has_builtin) && __has_builtin(__builtin_amdgcn_fdot2)
__device__ inline float fdot2(h2 a, h2 b, float c) {
    return __builtin_amdgcn_fdot2(a, b, c, false);
}
#else
__device__ inline float fdot2(h2 a, h2 b, float c) {
    return fmaf((float)a.x, (float)b.x, fmaf((float)a.y, (float)b.y, c));
}
#endif

// W fp32 [i][j][e][d] -> fp16 chunks Wc[((Gp*10+j)*8+k)*64 + lane], where
// lane = h*32+r, i = Gp*32+r, d = h*8+k; chunk holds e=0..7 halves of W[i,j,:,d].
__global__ void wprep_kernel(const float* __restrict__ W, int4* __restrict__ Wc) {
    const int t = blockIdx.x * blockDim.x + threadIdx.x;
    if (t >= NW / 8) return;
    const int lane = t & 63;
    const int h = lane >> 5, r = lane & 31;
    const int k = (t >> 6) & 7;
    const int r2 = t >> 9;  // Gp*10 + j
    const int j = r2 % NC, Gp = r2 / NC;
    const int i = Gp * 32 + r;
    const int d = h * 8 + k;
    const float* src = W + ((size_t)(i * NC + j) * IE) * DV + d;  // e-stride DV
    WChunk c;
#pragma unroll
    for (int e = 0; e < IE; ++e) c.h[e] = (_Float16)src[(size_t)e * DV];
    Wc[t] = c.v;
}

__global__ __launch_bounds__(TPB, 1) void caps_kernel(
    const float* __restrict__ X,     // [B, IC, IE] fp32
    const int4* __restrict__ Wc,     // coalesced fp16 layout (see wprep)
    const float* __restrict__ bias,  // [IC*NC] fp32
    float* __restrict__ out)         // [B, NC, DV]
{
    // LDS: 46080 + 46080 + 4608 + 7680 + 640 + 320 = 105,408 B -> 1 block/CU
    __shared__ __align__(16) float bias_s[NC * IC];  // [j][i]
    __shared__ __align__(16) float U[NC * IC];       // union: packed-h2 X (hat phase) / exp(lt) table (rounds)
    __shared__ float Zs[IC];                         // 1/sum_j exp(lt)
    __shared__ float s_part[NWAVE * SOUT];           // per-wave exclusive s slabs
    __shared__ float vc[SOUT];                       // cumulative v (f32)
    __shared__ __align__(16) h2 v2[SOUT / 2];        // cumulative v packed for fdot2

    const int b = blockIdx.x;
    const int tid = threadIdx.x;
    const int w = tid >> 6;   // wave 0..11
    const int g = tid & 63;
    const int h = g >> 5;     // d-half: d = h*8 + k
    const int r = g & 31;     // row within 32-row group

    // ---- stage bias -> bias_s[j][i]; consecutive tid -> consecutive i
    // (conflict-free LDS writes; strided global read is 46KB from L2, cheap) ----
    for (int idx = tid; idx < IC * NC; idx += TPB) {  // 15 iters
        const int j = idx / IC, i = idx - j * IC;
        bias_s[idx] = bias[i * NC + j];
    }
    // ---- stage X[b] packed as h2 into U: 16B per row i ----
    {
        const float4* xb = (const float4*)(X + (size_t)b * IC * IE);
        h2* xp = (h2*)U;
        for (int f = tid; f < IC * IE / 4; f += TPB) {  // 2304 float4, 3 iters
            const float4 v = xb[f];
            xp[f * 2 + 0] = h2{(_Float16)v.x, (_Float16)v.y};
            xp[f * 2 + 1] = h2{(_Float16)v.z, (_Float16)v.w};
        }
    }
    __syncthreads();

    // ---- hat phase: stream W once, hat resident in regs (fp16, 120 VGPRs) ----
    h2 hat2[NGPW][NC][4];
    {
        const h2* xp = (const h2*)U;
#pragma unroll
        for (int gl = 0; gl < NGPW; ++gl) {
            const int Gp = NGPW * w + gl;
            const int i = Gp * 32 + r;
            XFrag xu;
            xu.v = *(const int4*)(xp + (size_t)i * 4);
#pragma unroll
            for (int j = 0; j < NC; ++j) {
                const int4* wp = Wc + ((size_t)(Gp * NC + j)) * 512 + g;
                float hat[8];
                WChunk wk[4];
#pragma unroll
                for (int k = 0; k < 4; ++k) wk[k].v = wp[k * 64];
#pragma unroll
                for (int k = 0; k < 4; ++k) {
                    float a = 0.f;
#pragma unroll
                    for (int q = 0; q < 4; ++q) a = fdot2(xu.p[q], wk[k].p[q], a);
                    hat[k] = a;
                }
#pragma unroll
                for (int k = 0; k < 4; ++k) wk[k].v = wp[(k + 4) * 64];
#pragma unroll
                for (int k = 0; k < 4; ++k) {
                    float a = 0.f;
#pragma unroll
                    for (int q = 0; q < 4; ++q) a = fdot2(xu.p[q], wk[k].p[q], a);
                    hat[k + 4] = a;
                }
#pragma unroll
                for (int q = 0; q < 4; ++q)
                    hat2[gl][j][q] = h2{(_Float16)hat[2 * q], (_Float16)hat[2 * q + 1]};
            }
        }
    }

    // ---- 3 routing rounds, fully in-LDS ----
    for (int rd = 0; rd < 3; ++rd) {
        __syncthreads();  // orders U readers (X / prev loop2) before U writes; v2 ready

        // loop1: logits -> exp table U[j][i]
        if (rd == 0) {
            for (int idx = tid; idx < IC * NC; idx += TPB)  // 15 iters
                U[idx] = __expf(bias_s[idx]);
        } else {
#pragma unroll
            for (int gl = 0; gl < NGPW; ++gl) {
                const int Gp = NGPW * w + gl;
                const int i = Gp * 32 + r;
#pragma unroll
                for (int j = 0; j < NC; ++j) {
                    XFrag vv;
                    vv.v = *(const int4*)(v2 + (j * 8 + h * 4));
                    float ah = 0.f;
#pragma unroll
                    for (int q = 0; q < 4; ++q) ah = fdot2(hat2[gl][j][q], vv.p[q], ah);
                    const float lt = bias_s[j * IC + i] + ah + __shfl_xor(ah, 32);
                    if (h == 0) U[j * IC + i] = __expf(lt);
                }
            }
        }
        __syncthreads();

        // Z pass: 1/sum_j exp  (2 iters per thread)
        for (int idx = tid; idx < IC; idx += TPB) {
            float Z = 0.f;
#pragma unroll
            for (int j = 0; j < NC; ++j) Z += U[j * IC + idx];
            Zs[idx] = 1.f / Z;
        }
        __syncthreads();

        // loop2: per-j accumulate c*hat over this wave's 3 Gp groups, one
        // butterfly per j, plain store into this wave's exclusive s_part slab
#pragma unroll
        for (int j = 0; j < NC; ++j) {
            float s8[8] = {0.f, 0.f, 0.f, 0.f, 0.f, 0.f, 0.f, 0.f};
#pragma unroll
            for (int gl = 0; gl < NGPW; ++gl) {
                const int Gp = NGPW * w + gl;
                const int i = Gp * 32 + r;
                const float c = U[j * IC + i] * Zs[i];
#pragma unroll
                for (int q = 0; q < 4; ++q) {
                    s8[2 * q]     = fmaf(c, (float)hat2[gl][j][q].x, s8[2 * q]);
                    s8[2 * q + 1] = fmaf(c, (float)hat2[gl][j][q].y, s8[2 * q + 1]);
                }
            }
            // splitting butterfly over the 32 r-lanes of this d-half: 8->4->2->1
            float t4[4];
#pragma unroll
            for (int d = 0; d < 4; ++d) {
                const bool hi = (r & 16);
                const float mine = hi ? s8[d + 4] : s8[d];
                const float send = hi ? s8[d] : s8[d + 4];
                t4[d] = mine + __shfl_xor(send, 16);
            }
            float t2[2];
#pragma unroll
            for (int d = 0; d < 2; ++d) {
                const bool hi = (r & 8);
                const float mine = hi ? t4[d + 2] : t4[d];
                const float send = hi ? t4[d] : t4[d + 2];
                t2[d] = mine + __shfl_xor(send, 8);
            }
            float t1;
            {
                const bool hi = (r & 4);
                const float mine = hi ? t2[1] : t2[0];
                const float send = hi ? t2[0] : t2[1];
                t1 = mine + __shfl_xor(send, 4);
            }
            t1 += __shfl_xor(t1, 2);
            t1 += __shfl_xor(t1, 1);
            if ((r & 3) == 0) {
                const int dl = (r >> 2) & 7;  // bit map: r4->d2, r3->d1, r2->d0
                s_part[w * SOUT + j * DV + h * 8 + dl] = t1;
            }
        }
        __syncthreads();

        // squash: sum the 12 wave slabs, squash, update cumulative v / output
        if (tid < SOUT) {
            float sv = 0.f;
#pragma unroll
            for (int ww = 0; ww < NWAVE; ++ww) sv += s_part[ww * SOUT + tid];
            float s2 = sv * sv;
#pragma unroll
            for (int mk = 8; mk >= 1; mk >>= 1) s2 += __shfl_xor(s2, mk, 16);
            const float scale = sqrtf(s2) / (1.f + s2);
            const float vv = scale * sv;
            if (rd == 2) {
                out[(size_t)b * SOUT + tid] = vv;
            } else {
                const float vcum = (rd == 0) ? vv : (vc[tid] + vv);
                vc[tid] = vcum;
                const float oth = __shfl_xor(vcum, 1);
                if (!(tid & 1)) v2[tid >> 1] = h2{(_Float16)vcum, (_Float16)oth};
            }
        }
    }
}

extern "C" void kernel_launch(void* const* d_in, const int* in_sizes, int n_in,
                              void* d_out, int out_size, void* d_ws, size_t ws_size,
                              hipStream_t stream) {
    const float* X = (const float*)d_in[0];     // [256,1152,8]
    const float* W = (const float*)d_in[1];     // [1152,10,8,16]
    const float* bias = (const float*)d_in[2];  // [1,1152,10]
    float* out = (float*)d_out;

    int4* Wc = (int4*)d_ws;  // ws: Wc only (2.95 MB)

    wprep_kernel<<<dim3(720), dim3(256), 0, stream>>>(W, Wc);
    caps_kernel<<<dim3(NB), dim3(TPB), 0, stream>>>(X, Wc, bias, out);
}

// Round 4
// 412.834 us; speedup vs baseline: 1.7201x; 1.0084x over previous
//
#include <hip/hip_runtime.h>
#include <hip/hip_fp16.h>

// CapsuleLayer dynamic routing — round 8: pin waves-per-EU to kill the spill.
// Rounds 6/7 post-mortem: __launch_bounds__(TPB,1) only sets the MIN of the
// amdgpu-waves-per-eu range; the scheduler still targets the range MAX
// (default ~10, settled at 6/EU -> 84-VGPR budget) and spilled hat2 (120 regs)
// to scratch to chase occupancy that LDS (105KB -> 1 block/CU -> 3 waves/EU)
// makes unreachable. VGPR_Count=84 both with and without bounds; WRITE_SIZE
// 286MB = hat2 spill traffic. Fix: __attribute__((amdgpu_waves_per_eu(3,3)))
// pins the range so the RA budget = 512/3 = 170 >= ~150-reg demand.
// Everything else identical to round 7 (isolate the variable).

#define IC 1152
#define IE 8
#define NC 10
#define DV 16
#define NB 256
#define NW (IC * NC * IE * DV)  // 1,474,560
#define SOUT (NC * DV)          // 160
#define NWAVE 12
#define TPB (NWAVE * 64)        // 768
#define NGPW 3                  // Gp groups per wave (36 = 12*3)

typedef _Float16 h2 __attribute__((ext_vector_type(2)));
union WChunk { int4 v; h2 p[4]; _Float16 h[8]; };
union XFrag { int4 v; h2 p[4]; };

#if defined(__has_builtin) && __has_builtin(__builtin_amdgcn_fdot2)
__device__ inline float fdot2(h2 a, h2 b, float c) {
    return __builtin_amdgcn_fdot2(a, b, c, false);
}
#else
__device__ inline float fdot2(h2 a, h2 b, float c) {
    return fmaf((float)a.x, (float)b.x, fmaf((float)a.y, (float)b.y, c));
}
#endif

// W fp32 [i][j][e][d] -> fp16 chunks Wc[((Gp*10+j)*8+k)*64 + lane], where
// lane = h*32+r, i = Gp*32+r, d = h*8+k; chunk holds e=0..7 halves of W[i,j,:,d].
__global__ void wprep_kernel(const float* __restrict__ W, int4* __restrict__ Wc) {
    const int t = blockIdx.x * blockDim.x + threadIdx.x;
    if (t >= NW / 8) return;
    const int lane = t & 63;
    const int h = lane >> 5, r = lane & 31;
    const int k = (t >> 6) & 7;
    const int r2 = t >> 9;  // Gp*10 + j
    const int j = r2 % NC, Gp = r2 / NC;
    const int i = Gp * 32 + r;
    const int d = h * 8 + k;
    const float* src = W + ((size_t)(i * NC + j) * IE) * DV + d;  // e-stride DV
    WChunk c;
#pragma unroll
    for (int e = 0; e < IE; ++e) c.h[e] = (_Float16)src[(size_t)e * DV];
    Wc[t] = c.v;
}

__global__ __launch_bounds__(TPB)
__attribute__((amdgpu_waves_per_eu(3, 3)))
void caps_kernel(
    const float* __restrict__ X,     // [B, IC, IE] fp32
    const int4* __restrict__ Wc,     // coalesced fp16 layout (see wprep)
    const float* __restrict__ bias,  // [IC*NC] fp32
    float* __restrict__ out)         // [B, NC, DV]
{
    // LDS: 46080 + 46080 + 4608 + 7680 + 640 + 320 = 105,408 B -> 1 block/CU
    __shared__ __align__(16) float bias_s[NC * IC];  // [j][i]
    __shared__ __align__(16) float U[NC * IC];       // union: packed-h2 X (hat phase) / exp(lt) table (rounds)
    __shared__ float Zs[IC];                         // 1/sum_j exp(lt)
    __shared__ float s_part[NWAVE * SOUT];           // per-wave exclusive s slabs
    __shared__ float vc[SOUT];                       // cumulative v (f32)
    __shared__ __align__(16) h2 v2[SOUT / 2];        // cumulative v packed for fdot2

    const int b = blockIdx.x;
    const int tid = threadIdx.x;
    const int w = tid >> 6;   // wave 0..11
    const int g = tid & 63;
    const int h = g >> 5;     // d-half: d = h*8 + k
    const int r = g & 31;     // row within 32-row group

    // ---- stage bias -> bias_s[j][i]; consecutive tid -> consecutive i
    // (conflict-free LDS writes; strided global read is 46KB from L2, cheap) ----
    for (int idx = tid; idx < IC * NC; idx += TPB) {  // 15 iters
        const int j = idx / IC, i = idx - j * IC;
        bias_s[idx] = bias[i * NC + j];
    }
    // ---- stage X[b] packed as h2 into U: 16B per row i ----
    {
        const float4* xb = (const float4*)(X + (size_t)b * IC * IE);
        h2* xp = (h2*)U;
        for (int f = tid; f < IC * IE / 4; f += TPB) {  // 2304 float4, 3 iters
            const float4 v = xb[f];
            xp[f * 2 + 0] = h2{(_Float16)v.x, (_Float16)v.y};
            xp[f * 2 + 1] = h2{(_Float16)v.z, (_Float16)v.w};
        }
    }
    __syncthreads();

    // ---- hat phase: stream W once, hat resident in regs (fp16, 120 VGPRs) ----
    h2 hat2[NGPW][NC][4];
    {
        const h2* xp = (const h2*)U;
#pragma unroll
        for (int gl = 0; gl < NGPW; ++gl) {
            const int Gp = NGPW * w + gl;
            const int i = Gp * 32 + r;
            XFrag xu;
            xu.v = *(const int4*)(xp + (size_t)i * 4);
#pragma unroll
            for (int j = 0; j < NC; ++j) {
                const int4* wp = Wc + ((size_t)(Gp * NC + j)) * 512 + g;
                float hat[8];
                WChunk wk[4];
#pragma unroll
                for (int k = 0; k < 4; ++k) wk[k].v = wp[k * 64];
#pragma unroll
                for (int k = 0; k < 4; ++k) {
                    float a = 0.f;
#pragma unroll
                    for (int q = 0; q < 4; ++q) a = fdot2(xu.p[q], wk[k].p[q], a);
                    hat[k] = a;
                }
#pragma unroll
                for (int k = 0; k < 4; ++k) wk[k].v = wp[(k + 4) * 64];
#pragma unroll
                for (int k = 0; k < 4; ++k) {
                    float a = 0.f;
#pragma unroll
                    for (int q = 0; q < 4; ++q) a = fdot2(xu.p[q], wk[k].p[q], a);
                    hat[k + 4] = a;
                }
#pragma unroll
                for (int q = 0; q < 4; ++q)
                    hat2[gl][j][q] = h2{(_Float16)hat[2 * q], (_Float16)hat[2 * q + 1]};
            }
        }
    }

    // ---- 3 routing rounds, fully in-LDS ----
    for (int rd = 0; rd < 3; ++rd) {
        __syncthreads();  // orders U readers (X / prev loop2) before U writes; v2 ready

        // loop1: logits -> exp table U[j][i]
        if (rd == 0) {
            for (int idx = tid; idx < IC * NC; idx += TPB)  // 15 iters
                U[idx] = __expf(bias_s[idx]);
        } else {
#pragma unroll
            for (int gl = 0; gl < NGPW; ++gl) {
                const int Gp = NGPW * w + gl;
                const int i = Gp * 32 + r;
#pragma unroll
                for (int j = 0; j < NC; ++j) {
                    XFrag vv;
                    vv.v = *(const int4*)(v2 + (j * 8 + h * 4));
                    float ah = 0.f;
#pragma unroll
                    for (int q = 0; q < 4; ++q) ah = fdot2(hat2[gl][j][q], vv.p[q], ah);
                    const float lt = bias_s[j * IC + i] + ah + __shfl_xor(ah, 32);
                    if (h == 0) U[j * IC + i] = __expf(lt);
                }
            }
        }
        __syncthreads();

        // Z pass: 1/sum_j exp  (2 iters per thread)
        for (int idx = tid; idx < IC; idx += TPB) {
            float Z = 0.f;
#pragma unroll
            for (int j = 0; j < NC; ++j) Z += U[j * IC + idx];
            Zs[idx] = 1.f / Z;
        }
        __syncthreads();

        // loop2: per-j accumulate c*hat over this wave's 3 Gp groups, one
        // butterfly per j, plain store into this wave's exclusive s_part slab
#pragma unroll
        for (int j = 0; j < NC; ++j) {
            float s8[8] = {0.f, 0.f, 0.f, 0.f, 0.f, 0.f, 0.f, 0.f};
#pragma unroll
            for (int gl = 0; gl < NGPW; ++gl) {
                const int Gp = NGPW * w + gl;
                const int i = Gp * 32 + r;
                const float c = U[j * IC + i] * Zs[i];
#pragma unroll
                for (int q = 0; q < 4; ++q) {
                    s8[2 * q]     = fmaf(c, (float)hat2[gl][j][q].x, s8[2 * q]);
                    s8[2 * q + 1] = fmaf(c, (float)hat2[gl][j][q].y, s8[2 * q + 1]);
                }
            }
            // splitting butterfly over the 32 r-lanes of this d-half: 8->4->2->1
            float t4[4];
#pragma unroll
            for (int d = 0; d < 4; ++d) {
                const bool hi = (r & 16);
                const float mine = hi ? s8[d + 4] : s8[d];
                const float send = hi ? s8[d] : s8[d + 4];
                t4[d] = mine + __shfl_xor(send, 16);
            }
            float t2[2];
#pragma unroll
            for (int d = 0; d < 2; ++d) {
                const bool hi = (r & 8);
                const float mine = hi ? t4[d + 2] : t4[d];
                const float send = hi ? t4[d] : t4[d + 2];
                t2[d] = mine + __shfl_xor(send, 8);
            }
            float t1;
            {
                const bool hi = (r & 4);
                const float mine = hi ? t2[1] : t2[0];
                const float send = hi ? t2[0] : t2[1];
                t1 = mine + __shfl_xor(send, 4);
            }
            t1 += __shfl_xor(t1, 2);
            t1 += __shfl_xor(t1, 1);
            if ((r & 3) == 0) {
                const int dl = (r >> 2) & 7;  // bit map: r4->d2, r3->d1, r2->d0
                s_part[w * SOUT + j * DV + h * 8 + dl] = t1;
            }
        }
        __syncthreads();

        // squash: sum the 12 wave slabs, squash, update cumulative v / output
        if (tid < SOUT) {
            float sv = 0.f;
#pragma unroll
            for (int ww = 0; ww < NWAVE; ++ww) sv += s_part[ww * SOUT + tid];
            float s2 = sv * sv;
#pragma unroll
            for (int mk = 8; mk >= 1; mk >>= 1) s2 += __shfl_xor(s2, mk, 16);
            const float scale = sqrtf(s2) / (1.f + s2);
            const float vv = scale * sv;
            if (rd == 2) {
                out[(size_t)b * SOUT + tid] = vv;
            } else {
                const float vcum = (rd == 0) ? vv : (vc[tid] + vv);
                vc[tid] = vcum;
                const float oth = __shfl_xor(vcum, 1);
                if (!(tid & 1)) v2[tid >> 1] = h2{(_Float16)vcum, (_Float16)oth};
            }
        }
    }
}

extern "C" void kernel_launch(void* const* d_in, const int* in_sizes, int n_in,
                              void* d_out, int out_size, void* d_ws, size_t ws_size,
                              hipStream_t stream) {
    const float* X = (const float*)d_in[0];     // [256,1152,8]
    const float* W = (const float*)d_in[1];     // [1152,10,8,16]
    const float* bias = (const float*)d_in[2];  // [1,1152,10]
    float* out = (float*)d_out;

    int4* Wc = (int4*)d_ws;  // ws: Wc only (2.95 MB)

    wprep_kernel<<<dim3(720), dim3(256), 0, stream>>>(W, Wc);
    caps_kernel<<<dim3(NB), dim3(TPB), 0, stream>>>(X, Wc, bias, out);
}